// Round 8
// baseline (186.090 us; speedup 1.0000x reference)
//
#include <hip/hip_runtime.h>
#include <stdint.h>
#include <stddef.h>

// Problem constants
#define BSZ 128
#define CIN 32
#define COUT 32
#define HN 4096
#define K7 7
#define NTOT (BSZ*CIN*HN)     // 16,777,216 elements
#define NBH  (BSZ*HN)         // 524,288 (b,h) pairs

typedef __attribute__((ext_vector_type(8))) short short8;
typedef __attribute__((ext_vector_type(4))) float f32x4;
typedef __attribute__((ext_vector_type(4))) unsigned int u32x4;
typedef __attribute__((ext_vector_type(2))) unsigned int u32x2;

// ws layout (bytes). NOTE: xt lives in the UPPER HALF OF d_out (d_out is 67MB
// f32; xt is 33.5MB bf16, dead before kbn overwrites d_out).
#define WS_OB   0            // bf16 out_pre[B][COUT][H]     : 33,554,432 B
#define WS_WT   33554432     // bf16 wt[o][kk][c]            : 14,336 B
#define WS_NBR  33568768     // int32 nbr_pack[H][8]         : 131,072 B
#define WS_INVD 33699840     // float invd[H]                : 16,384 B
#define WS_OSTP 33716224     // float ostatp[256][64]        : 65,536 B
#define WS_OST  33781760     // float ostat[64] = {sc[32], sh[32]} : 256 B

// LESSONS LEDGER:
// R3: no __threadfence() in wide kernels (per-block L2-writeback op tripled
//     kconv at identical traffic).
// R4: __builtin_nontemporal_* is NET NEGATIVE on every stream here. Plain.
// R6: halving gather *line* traffic (b-pair packing) = null. Not line-BW.
// R7: L2-warming = null. Not miss *latency*.
// => Working model: kconv bound by per-CU read-miss PROCESSING RATE
//    (~7 cyc per 64B granule; ~14.3K lookups/CU). Writes are cheap
//    (R0 vs R1: 8x write segs cost only 4.5us). Lever: REMOVE lookups
//    by serving gathers from LDS.

__device__ __forceinline__ unsigned short f32_to_bf16(float f){
    union { float f; uint32_t u; } v; v.f = f;
    uint32_t u = v.u;
    return (unsigned short)((u + 0x7FFFu + ((u >> 16) & 1u)) >> 16);
}
__device__ __forceinline__ float bf16_to_f32(unsigned short h){
    union { uint32_t u; float f; } v; v.u = ((uint32_t)h) << 16;
    return v.f;
}

// ---------------------------------------------------------------------------
// ktrans: transpose x[B][C][H] f32 -> xt[B][H][C] bf16 (flat layout).
// grid = 128 b * 16 h-tiles(256h) = 2048 blocks of 256.
// kinit fold: blocks 0..15 neighbor table + invd + zero ostatp; block 16
// packs weights.
__global__ void ktrans(const float* __restrict__ x,
                       unsigned short* __restrict__ xt,
                       const int* __restrict__ nbr,
                       const float* __restrict__ w,
                       int* __restrict__ nbr_pack,
                       float* __restrict__ invd,
                       unsigned short* __restrict__ wt,
                       float* __restrict__ ostatp){
    __shared__ float tile[32][260];       // rows 16B-aligned (260*4=1040)
    int b  = blockIdx.x >> 4;
    int h0 = (blockIdx.x & 15) << 8;
    int t  = threadIdx.x;
    #pragma unroll
    for (int l = 0; l < 8; l++){
        int linear = l*256 + t;
        int c  = linear >> 6;
        int h4 = linear & 63;
        f32x4 v = *(const f32x4*)(x + ((size_t)(b*CIN + c))*HN + h0 + h4*4);
        *(f32x4*)&tile[c][h4*4] = v;      // contiguous b128 stores: conflict-free
    }
    __syncthreads();
    int cg = (t & 3) * 8;
    int hw = t >> 2;                      // 0..63
    #pragma unroll
    for (int r = 0; r < 4; r++){
        int h = r*64 + hw;
        alignas(16) unsigned short tmp[8];
        #pragma unroll
        for (int j = 0; j < 8; j++) tmp[j] = f32_to_bf16(tile[cg + j][h]);
        *(u32x4*)(xt + ((size_t)(b*HN + h0 + h))*32 + cg) = *(const u32x4*)tmp;
    }
    // ---- folded kinit work (independent of above; no extra sync needed) ----
    if (blockIdx.x < 16){
        int h = blockIdx.x*256 + t;       // 0..4095
        #pragma unroll
        for (int j = 0; j < 4; j++) ostatp[h*4 + j] = 0.0f;   // 16384 floats
        int cnt = 0;
        int pk[8];
        #pragma unroll
        for (int j = 0; j < 6; j++){
            int iv = nbr[h*6 + j];
            if (iv >= HN) iv = HN - 1;    // safety clamp (never expected)
            if (iv >= 0) cnt++; else iv = -1;
            pk[j] = iv;
        }
        pk[6] = cnt; pk[7] = 0;
        #pragma unroll
        for (int j = 0; j < 8; j++) nbr_pack[h*8 + j] = pk[j];
        invd[h] = 1.0f / ((float)cnt + 1.0f + 1e-6f);
    } else if (blockIdx.x == 16){
        for (int i = t; i < COUT*K7*CIN; i += 256){
            int o  = i / (K7*CIN);
            int kk = (i / CIN) % K7;
            int c  = i % CIN;
            wt[i] = f32_to_bf16(w[(o*CIN + c)*K7 + kk]);
        }
    }
}

// ---------------------------------------------------------------------------
// kconv (R8 rewrite): one 1024-thread block per CU; 256 blocks total.
// blk = [xcd:3][j:5]; b = xcd*16 + (j>>1); hh = j&1. Block covers h-half
// [hh*2048, +2048) of one b. LDS: (a) sx = the block's OWN 2048 xt rows
// (128KB, XOR-swizzled chunks: chunk q of row r at q^(r&3)) — serves the
// self tap + ~50% of neighbor taps from the DS pipe instead of the L1-miss
// path; (b) swt = weight fragments (14KB) — af read per-iter from LDS to
// keep VGPR<=128 at 16 waves/CU.
// Stores: direct 2B scattered (R0-style; writes measured cheap, no LDS left
// for otile).
__global__ __launch_bounds__(1024, 4) void kconv(
    const unsigned short* __restrict__ xt,
    const unsigned short* __restrict__ wt,
    const int* __restrict__ nbrp,
    const float* __restrict__ invd,
    unsigned short* __restrict__ ob,
    float* __restrict__ ostatp)
{
    __shared__ unsigned short sx[2048*32];    // 131,072 B (staged half-slice)
    __shared__ unsigned short swt[COUT*K7*CIN]; // 14,336 B

    int t    = threadIdx.x;
    int lane = t & 63;
    int wv   = t >> 6;                    // 0..15
    int n    = lane & 15;
    int quad = lane >> 4;
    int xcd  = blockIdx.x & 7;
    int j    = blockIdx.x >> 3;           // 0..31
    int b    = xcd*16 + (j >> 1);
    int hh   = j & 1;                     // which h-half
    int hoff = hh << 11;                  // hh*2048

    const unsigned short* xb = xt + (size_t)b*HN*CIN;

    // ---- stage: own half-slice (2048 rows x 64B) + weights into LDS ----
    #pragma unroll
    for (int rr = 0; rr < 2; rr++){
        int r = rr*1024 + t;              // local row 0..2047
        const u32x4* src = (const u32x4*)(xb + (size_t)(hoff + r)*CIN);
        #pragma unroll
        for (int q = 0; q < 4; q++){
            // swizzled chunk: chunk q of row r lands at q^(r&3)
            *(u32x4*)(sx + r*32 + ((q ^ (r & 3))*8)) = src[q];
        }
    }
    if (t < (COUT*K7*CIN)/8){
        *(u32x4*)(swt + t*8) = *(const u32x4*)(wt + t*8);
    }
    __syncthreads();

    float sacc[8]  = {0,0,0,0,0,0,0,0};
    float sacc2[8] = {0,0,0,0,0,0,0,0};
    const short8 zero8 = {0,0,0,0,0,0,0,0};

    int hbase = hoff + wv*128;            // this wave: h in [hbase, hbase+128)

    // prefetch tile 0's neighbor rows + invd
    int h = hbase + n;
    int4 na = *(const int4*)(nbrp + h*8);
    int4 nb = *(const int4*)(nbrp + h*8 + 4);
    float idv = invd[h];

    #pragma unroll 1
    for (int it = 0; it < 8; it++){
        // prefetch next tile's table entries (dummy-reload current on last)
        int hn = hbase + (it < 7 ? it+1 : it)*16 + n;
        int4 na2 = *(const int4*)(nbrp + hn*8);
        int4 nb2 = *(const int4*)(nbrp + hn*8 + 4);
        float idv2 = invd[hn];

        int hc = hbase + it*16 + n;       // global h
        short8 bfr[K7];
        {   // self tap: ALWAYS in the staged half
            int rl = hc - hoff;
            bfr[0] = *(const short8*)(sx + rl*32 + ((quad ^ (rl & 3))*8));
        }
        int rows[6] = {na.x, na.y, na.z, na.w, nb.x, nb.y};
        #pragma unroll
        for (int kk = 0; kk < 6; kk++){
            int row = rows[kk];
            int rowc = row < 0 ? 0 : row;
            int rl = rowc - hoff;
            short8 v;
            if ((unsigned)rl < 2048u){
                v = *(const short8*)(sx + rl*32 + ((quad ^ (rl & 3))*8));
            } else {
                v = *(const short8*)(xb + (size_t)rowc*CIN + quad*8);
            }
            if (row < 0) v = zero8;
            bfr[kk+1] = v;
        }
        f32x4 acc0 = {0.f,0.f,0.f,0.f};
        f32x4 acc1 = {0.f,0.f,0.f,0.f};
        #pragma unroll
        for (int kk = 0; kk < K7; kk++){
            short8 a0 = *(const short8*)(swt + ((n     )*K7 + kk)*CIN + quad*8);
            short8 a1 = *(const short8*)(swt + ((n + 16)*K7 + kk)*CIN + quad*8);
            acc0 = __builtin_amdgcn_mfma_f32_16x16x32_bf16(a0, bfr[kk], acc0, 0, 0, 0);
            acc1 = __builtin_amdgcn_mfma_f32_16x16x32_bf16(a1, bfr[kk], acc1, 0, 0, 0);
        }
        // epilogue: D[row=quad*4+r][col=n]; o = mt*16+quad*4+r.
        // Direct 2B stores (writes measured cheap; no otile LDS available).
        #pragma unroll
        for (int mt = 0; mt < 2; mt++){
            f32x4 a = mt ? acc1 : acc0;
            #pragma unroll
            for (int r = 0; r < 4; r++){
                int o = mt*16 + quad*4 + r;
                float v = a[r]*idv;
                ob[((size_t)(b*COUT + o))*HN + hc] = f32_to_bf16(v);
                sacc[mt*4 + r]  += v;
                sacc2[mt*4 + r] += v*v;
            }
        }
        na = na2; nb = nb2; idv = idv2;
    }

    // reduce BN partials over the 16 n-lanes
    #pragma unroll
    for (int bit = 1; bit < 16; bit <<= 1){
        #pragma unroll
        for (int i = 0; i < 8; i++){
            sacc[i]  += __shfl_xor(sacc[i],  bit);
            sacc2[i] += __shfl_xor(sacc2[i], bit);
        }
    }
    if (n == 0){
        int slot = blockIdx.x;            // 256 blocks -> private slot each
        #pragma unroll
        for (int mt = 0; mt < 2; mt++)
            #pragma unroll
            for (int r = 0; r < 4; r++){
                int o = mt*16 + quad*4 + r;
                atomicAdd(&ostatp[slot*64 + o],      sacc[mt*4 + r]);
                atomicAdd(&ostatp[slot*64 + 32 + o], sacc2[mt*4 + r]);
            }
    }
}

// ---------------------------------------------------------------------------
// kred: fold ostatp[256][64] -> ostat = {sc[32], sh[32]}. One block of 256.
__global__ void kred(const float* __restrict__ ostatp,
                     float* __restrict__ ostat,
                     const float* __restrict__ gamma,
                     const float* __restrict__ beta){
    __shared__ float part[4][64];
    int t = threadIdx.x;
    int a = t & 63;
    int g = t >> 6;
    float s = 0.0f;
    #pragma unroll
    for (int j = 0; j < 64; j++)
        s += ostatp[(g*64 + j)*64 + a];
    part[g][a] = s;
    __syncthreads();
    if (t < 64)
        part[0][t] = part[0][t] + part[1][t] + part[2][t] + part[3][t];
    __syncthreads();
    if (t < 32){
        float mean = part[0][t]      * (1.0f/(float)NBH);
        float var  = part[0][32 + t] * (1.0f/(float)NBH) - mean*mean;
        float sc = gamma[t] * rsqrtf(var + 1e-5f);
        ostat[t]      = sc;
        ostat[32 + t] = beta[t] - mean*sc;
    }
}

// ---------------------------------------------------------------------------
// kbn: read bf16 out_pre, apply precomputed scale/shift, write f32 d_out.
// Per-thread: one u32x2 (4 bf16) load -> one f32x4 store => every store
// instruction is a DENSE 1KB/wave line write. Plain accesses (R4: nt hurt).
__global__ void kbn(const unsigned short* __restrict__ ob,
                    float* __restrict__ out,
                    const float* __restrict__ ostat){
    __shared__ float sc[32], sh[32];
    int t = threadIdx.x;
    if (t < 32){ sc[t] = ostat[t]; sh[t] = ostat[32 + t]; }
    __syncthreads();
    int gid = blockIdx.x*256 + t;
    const u32x2* ob2 = (const u32x2*)ob;
    f32x4* out4 = (f32x4*)out;
    #pragma unroll
    for (int k = 0; k < 8; k++){
        int i = gid + k*(2048*256);               // i < NTOT/4 = 4,194,304
        int o = (i >> 10) & 31;                   // (i*4 / 4096) % 32
        u32x2 raw = *(ob2 + i);
        const unsigned short* p = (const unsigned short*)&raw;
        float s = sc[o], bsh = sh[o];
        f32x4 r;
        r.x = bf16_to_f32(p[0])*s + bsh;
        r.y = bf16_to_f32(p[1])*s + bsh;
        r.z = bf16_to_f32(p[2])*s + bsh;
        r.w = bf16_to_f32(p[3])*s + bsh;
        *(out4 + i) = r;
    }
}

// ---------------------------------------------------------------------------
extern "C" void kernel_launch(void* const* d_in, const int* in_sizes, int n_in,
                              void* d_out, int out_size, void* d_ws, size_t ws_size,
                              hipStream_t stream) {
    const float* x      = (const float*)d_in[0];
    const float* weight = (const float*)d_in[1];
    // d_in[2] = bias  — exactly cancelled by BatchNorm mean subtraction
    const float* gamma  = (const float*)d_in[3];
    const float* beta   = (const float*)d_in[4];
    const int*   nbr    = (const int*)d_in[5];   // int64 in reference -> int32 from harness
    // d_in[6] = groups (==1), ignored

    char* ws = (char*)d_ws;
    unsigned short* ob    = (unsigned short*)(ws + WS_OB);
    unsigned short* wt    = (unsigned short*)(ws + WS_WT);
    int*            nbrp  = (int*)(ws + WS_NBR);
    float*          invd  = (float*)(ws + WS_INVD);
    float*          ostatp= (float*)(ws + WS_OSTP);
    float*          ostat = (float*)(ws + WS_OST);
    float*          out   = (float*)d_out;
    // xt (bf16, 33.5MB) lives in the upper half of d_out; dead before kbn
    // overwrites d_out (stream-ordered).
    unsigned short* xt    = (unsigned short*)d_out + 16777216;

    ktrans<<<2048, 256, 0, stream>>>(x, xt, nbr, weight, nbrp, invd, wt, ostatp);
    kconv <<<256, 1024, 0, stream>>>(xt, wt, nbrp, invd, ob, ostatp);
    kred  <<<1,    256, 0, stream>>>(ostatp, ostat, gamma, beta);
    kbn   <<<2048, 256, 0, stream>>>(ob, out, ostat);
}

// Round 9
// 178.204 us; speedup vs baseline: 1.0443x; 1.0443x over previous
//
#include <hip/hip_runtime.h>
#include <stdint.h>
#include <stddef.h>

// Problem constants
#define BSZ 128
#define CIN 32
#define COUT 32
#define HN 4096
#define K7 7
#define NTOT (BSZ*CIN*HN)     // 16,777,216 elements
#define NBH  (BSZ*HN)         // 524,288 (b,h) pairs

typedef __attribute__((ext_vector_type(8))) short short8;
typedef __attribute__((ext_vector_type(4))) float f32x4;
typedef __attribute__((ext_vector_type(4))) unsigned int u32x4;
typedef __attribute__((ext_vector_type(2))) unsigned int u32x2;

// ws layout (bytes). NOTE: xh lives in the UPPER HALF OF d_out (d_out is 67MB
// f32; xh is 33.5MB bf16, dead before kbn overwrites d_out).
#define WS_OB   0            // bf16 ob[h][o][b]             : 33,554,432 B
#define WS_WT   33554432     // bf16 wt[o][kk][c]            : 14,336 B
#define WS_NBR  33568768     // int32 nbr_pack[H][8]         : 131,072 B
#define WS_INVD 33699840     // float invd[H]                : 16,384 B
#define WS_OSTP 33716224     // float ostatp[256][64]        : 65,536 B
#define WS_OST  33781760     // float ostat[64] = {sc[32], sh[32]} : 256 B

// LESSONS LEDGER:
// R3: no __threadfence() in wide kernels (L2-writeback per block: 3x).
// R4: __builtin_nontemporal_* NET NEGATIVE on every stream. Plain only.
// R6: halving gather *lines* (b-pair) = null. Not line-BW bound.
// R7: L2-warming = null. Not miss-latency bound.
// R8: LDS-serving 57% of taps lost to its own staging traffic + conflicts.
// => kconv time tracks SCATTERED 64B-segment lookups (~7cyc/seg/CU);
//    ktrans shows DENSE segments run ~3x faster (~2.4cyc). R9 tests the
//    dense-vs-scattered axis: transpose the GEMM so gathers are 8KB-dense.

__device__ __forceinline__ unsigned short f32_to_bf16(float f){
    union { float f; uint32_t u; } v; v.f = f;
    uint32_t u = v.u;
    return (unsigned short)((u + 0x7FFFu + ((u >> 16) & 1u)) >> 16);
}
__device__ __forceinline__ float bf16_to_f32(unsigned short h){
    union { uint32_t u; float f; } v; v.u = ((uint32_t)h) << 16;
    return v.f;
}

// ---------------------------------------------------------------------------
// ktrans: x[b][c][h] f32 -> xh[h][b*32+c] bf16 (one 8KB row per h).
// grid = 128 b * 16 h-tiles(256h) = 2048 blocks of 256. Each block fills the
// 64B (b,c)-chunk of 256 consecutive h-rows. Writes are 64B granules at 8KB
// stride (write segs ~2K/CU: cheap per R0 evidence).
// kinit fold: blocks 0..15 neighbor table + invd + zero ostatp; block 16
// packs weights.
__global__ void ktrans(const float* __restrict__ x,
                       unsigned short* __restrict__ xh,
                       const int* __restrict__ nbr,
                       const float* __restrict__ w,
                       int* __restrict__ nbr_pack,
                       float* __restrict__ invd,
                       unsigned short* __restrict__ wt,
                       float* __restrict__ ostatp){
    __shared__ float tile[32][260];       // rows 16B-aligned (260*4=1040)
    int b  = blockIdx.x >> 4;
    int h0 = (blockIdx.x & 15) << 8;
    int t  = threadIdx.x;
    #pragma unroll
    for (int l = 0; l < 8; l++){
        int linear = l*256 + t;
        int c  = linear >> 6;
        int h4 = linear & 63;
        f32x4 v = *(const f32x4*)(x + ((size_t)(b*CIN + c))*HN + h0 + h4*4);
        *(f32x4*)&tile[c][h4*4] = v;      // contiguous b128 stores: conflict-free
    }
    __syncthreads();
    // one thread per h: read column (2-way bank alias: free), write 64B chunk
    {
        int h = t;
        alignas(16) unsigned short tmp[32];
        #pragma unroll
        for (int c = 0; c < 32; c++) tmp[c] = f32_to_bf16(tile[c][h]);
        unsigned short* dst = xh + (size_t)(h0 + h)*(BSZ*CIN/HN*0 + 4096) + b*32;
        #pragma unroll
        for (int q = 0; q < 4; q++)
            *(u32x4*)(dst + q*8) = *(const u32x4*)(tmp + q*8);
    }
    // ---- folded kinit work (independent of above; no extra sync needed) ----
    if (blockIdx.x < 16){
        int h = blockIdx.x*256 + t;       // 0..4095
        #pragma unroll
        for (int j = 0; j < 4; j++) ostatp[h*4 + j] = 0.0f;   // 16384 floats
        int cnt = 0;
        int pk[8];
        #pragma unroll
        for (int j = 0; j < 6; j++){
            int iv = nbr[h*6 + j];
            if (iv >= HN) iv = HN - 1;    // safety clamp (never expected)
            if (iv >= 0) cnt++; else iv = -1;
            pk[j] = iv;
        }
        pk[6] = cnt; pk[7] = 0;
        #pragma unroll
        for (int j = 0; j < 8; j++) nbr_pack[h*8 + j] = pk[j];
        invd[h] = 1.0f / ((float)cnt + 1.0f + 1e-6f);
    } else if (blockIdx.x == 16){
        for (int i = t; i < COUT*K7*CIN; i += 256){
            int o  = i / (K7*CIN);
            int kk = (i / CIN) % K7;
            int c  = i % CIN;
            wt[i] = f32_to_bf16(w[(o*CIN + c)*K7 + kk]);
        }
    }
}

// ---------------------------------------------------------------------------
// kconv (R9): DENSE-gather GEMM. Grid 1024 blocks x 256 thr (4 waves);
// block handles 4 h's. Per h: out[o=32][b=128] = sum_k W_k x xh[row_k(h)],
// row indices UNIFORM per h -> every B-fragment load is a fully-coalesced
// 1KB wave read (16 b x 64B consecutive). Zero scattered lookups.
// Wave w owns b-range [w*32, w*32+32): 2 b-tiles x 2 o-tiles x 7 taps =
// 28 MFMAs/h. D staged in otile[o][b] (8KB), written as one dense 8KB row
// ob[h][o*128+b]. Stats accumulated as before.
__global__ __launch_bounds__(256, 4) void kconv(
    const unsigned short* __restrict__ xh,
    const unsigned short* __restrict__ wt,
    const int* __restrict__ nbrp,
    const float* __restrict__ invd,
    unsigned short* __restrict__ ob,
    float* __restrict__ ostatp)
{
    __shared__ unsigned short otile[COUT*BSZ];   // 8,192 B [o][b]

    int t    = threadIdx.x;
    int lane = t & 63;
    int wv   = t >> 6;                    // 0..3 -> b-range wv*32
    int n    = lane & 15;
    int quad = lane >> 4;

    // A fragments (W): lane holds W[o=n+16mt][ik=kk*32 + quad*8 + jj]
    short8 af[2][K7];
    #pragma unroll
    for (int mt = 0; mt < 2; mt++){
        int o = n + 16*mt;
        #pragma unroll
        for (int kk = 0; kk < K7; kk++)
            af[mt][kk] = *(const short8*)(wt + (size_t)(o*K7 + kk)*CIN + quad*8);
    }

    float sacc[8]  = {0,0,0,0,0,0,0,0};
    float sacc2[8] = {0,0,0,0,0,0,0,0};
    const short8 zero8 = {0,0,0,0,0,0,0,0};

    int hbase = blockIdx.x * 4;

    #pragma unroll 1
    for (int hi = 0; hi < 4; hi++){
        int h = hbase + hi;
        // uniform per-h metadata (scalarizes: h is wave-uniform)
        const int* np = nbrp + h*8;
        int rows[K7];
        rows[0] = h;
        #pragma unroll
        for (int j = 0; j < 6; j++) rows[j+1] = np[j];
        float idv = invd[h];

        f32x4 a00 = {0.f,0.f,0.f,0.f};   // bt0, o-tile 0
        f32x4 a01 = {0.f,0.f,0.f,0.f};   // bt0, o-tile 1
        f32x4 a10 = {0.f,0.f,0.f,0.f};   // bt1, o-tile 0
        f32x4 a11 = {0.f,0.f,0.f,0.f};   // bt1, o-tile 1
        int bb0 = (wv*2    )*16 + n;
        int bb1 = (wv*2 + 1)*16 + n;
        #pragma unroll
        for (int k = 0; k < K7; k++){
            int row  = rows[k];
            int rowc = row < 0 ? 0 : row;
            const unsigned short* rp = xh + (size_t)rowc*4096;
            short8 v0 = *(const short8*)(rp + bb0*32 + quad*8);   // 1KB dense/wave
            short8 v1 = *(const short8*)(rp + bb1*32 + quad*8);
            if (row < 0){ v0 = zero8; v1 = zero8; }
            a00 = __builtin_amdgcn_mfma_f32_16x16x32_bf16(af[0][k], v0, a00, 0, 0, 0);
            a01 = __builtin_amdgcn_mfma_f32_16x16x32_bf16(af[1][k], v0, a01, 0, 0, 0);
            a10 = __builtin_amdgcn_mfma_f32_16x16x32_bf16(af[0][k], v1, a10, 0, 0, 0);
            a11 = __builtin_amdgcn_mfma_f32_16x16x32_bf16(af[1][k], v1, a11, 0, 0, 0);
        }
        // epilogue: D col = b(lane&15), row = o = mt*16 + quad*4 + r
        #pragma unroll
        for (int bt = 0; bt < 2; bt++){
            int bb = bt ? bb1 : bb0;
            #pragma unroll
            for (int mt = 0; mt < 2; mt++){
                f32x4 a = bt ? (mt ? a11 : a10) : (mt ? a01 : a00);
                #pragma unroll
                for (int r = 0; r < 4; r++){
                    int o = mt*16 + quad*4 + r;
                    float v = a[r]*idv;
                    otile[o*BSZ + bb] = f32_to_bf16(v);
                    sacc[mt*4 + r]  += v;
                    sacc2[mt*4 + r] += v*v;
                }
            }
        }
        __syncthreads();
        // dense 8KB row write: thread t -> 32B (two u32x4)
        {
            u32x4 v0 = *(const u32x4*)(otile + t*16);
            u32x4 v1 = *(const u32x4*)(otile + t*16 + 8);
            *(u32x4*)(ob + (size_t)h*4096 + t*16)     = v0;
            *(u32x4*)(ob + (size_t)h*4096 + t*16 + 8) = v1;
        }
        __syncthreads();                  // before next h overwrites otile
    }

    // reduce BN partials over the 16 n-lanes (b within tile; bt/h summed)
    #pragma unroll
    for (int bit = 1; bit < 16; bit <<= 1){
        #pragma unroll
        for (int i = 0; i < 8; i++){
            sacc[i]  += __shfl_xor(sacc[i],  bit);
            sacc2[i] += __shfl_xor(sacc2[i], bit);
        }
    }
    if (n == 0){
        int slot = blockIdx.x & 255;
        #pragma unroll
        for (int mt = 0; mt < 2; mt++)
            #pragma unroll
            for (int r = 0; r < 4; r++){
                int o = mt*16 + quad*4 + r;
                atomicAdd(&ostatp[slot*64 + o],      sacc[mt*4 + r]);
                atomicAdd(&ostatp[slot*64 + 32 + o], sacc2[mt*4 + r]);
            }
    }
}

// ---------------------------------------------------------------------------
// kred: fold ostatp[256][64] -> ostat = {sc[32], sh[32]}. One block of 256.
__global__ void kred(const float* __restrict__ ostatp,
                     float* __restrict__ ostat,
                     const float* __restrict__ gamma,
                     const float* __restrict__ beta){
    __shared__ float part[4][64];
    int t = threadIdx.x;
    int a = t & 63;
    int g = t >> 6;
    float s = 0.0f;
    #pragma unroll
    for (int j = 0; j < 64; j++)
        s += ostatp[(g*64 + j)*64 + a];
    part[g][a] = s;
    __syncthreads();
    if (t < 64)
        part[0][t] = part[0][t] + part[1][t] + part[2][t] + part[3][t];
    __syncthreads();
    if (t < 32){
        float mean = part[0][t]      * (1.0f/(float)NBH);
        float var  = part[0][32 + t] * (1.0f/(float)NBH) - mean*mean;
        float sc = gamma[t] * rsqrtf(var + 1e-5f);
        ostat[t]      = sc;
        ostat[32 + t] = beta[t] - mean*sc;
    }
}

// ---------------------------------------------------------------------------
// kbn (R9): transpose-scale ob[h][o][b] bf16 -> out[b][o][h] f32.
// Tile = [64 h][64 b] for one o; 2048 blocks x 2 tiles. Reads: 128B/h-row
// (dense granules). Writes: lanes cover 4 full 256B b-rows per instruction
// (1KB dense). LDS tile[64][65] f32 (odd pad -> 2-way bank alias, free);
// scale/shift applied at stage time (o uniform per tile).
__global__ void kbn(const unsigned short* __restrict__ ob,
                    float* __restrict__ out,
                    const float* __restrict__ ostat){
    __shared__ float tile[64][65];
    int t = threadIdx.x;
    #pragma unroll 1
    for (int ti2 = 0; ti2 < 2; ti2++){
        int ti = blockIdx.x*2 + ti2;      // 0..4095
        int o  = ti & 31;
        int bh = ti >> 5;                 // 0..127
        int b0 = (bh & 1) * 64;
        int h0 = (bh >> 1) * 64;
        float s   = ostat[o];
        float bsh = ostat[32 + o];
        if (ti2) __syncthreads();         // protect tile reuse
        // stage 64h x 64b, scaled to f32
        {
            int hl = t >> 2;              // 0..63
            int ck = t & 3;               // 16-short chunk
            const unsigned short* src = ob + (size_t)(h0 + hl)*4096 + o*BSZ + b0 + ck*16;
            u32x4 p0 = *(const u32x4*)(src);
            u32x4 p1 = *(const u32x4*)(src + 8);
            const unsigned short* pp0 = (const unsigned short*)&p0;
            const unsigned short* pp1 = (const unsigned short*)&p1;
            #pragma unroll
            for (int j = 0; j < 8; j++)
                tile[hl][ck*16 + j]     = bf16_to_f32(pp0[j])*s + bsh;
            #pragma unroll
            for (int j = 0; j < 8; j++)
                tile[hl][ck*16 + 8 + j] = bf16_to_f32(pp1[j])*s + bsh;
        }
        __syncthreads();
        // write out: lane group covers full 256B b-rows densely
        {
            int piece = t & 15;           // 16B piece within 256B b-row
            int brow  = t >> 4;           // 0..15
            #pragma unroll
            for (int pass = 0; pass < 4; pass++){
                int b = pass*16 + brow;
                f32x4 v;
                #pragma unroll
                for (int j = 0; j < 4; j++)
                    v[j] = tile[piece*4 + j][b];
                *(f32x4*)(out + ((size_t)(b0 + b)*COUT + o)*HN + h0 + piece*4) = v;
            }
        }
    }
}

// ---------------------------------------------------------------------------
extern "C" void kernel_launch(void* const* d_in, const int* in_sizes, int n_in,
                              void* d_out, int out_size, void* d_ws, size_t ws_size,
                              hipStream_t stream) {
    const float* x      = (const float*)d_in[0];
    const float* weight = (const float*)d_in[1];
    // d_in[2] = bias  — exactly cancelled by BatchNorm mean subtraction
    const float* gamma  = (const float*)d_in[3];
    const float* beta   = (const float*)d_in[4];
    const int*   nbr    = (const int*)d_in[5];   // int64 in reference -> int32 from harness
    // d_in[6] = groups (==1), ignored

    char* ws = (char*)d_ws;
    unsigned short* ob    = (unsigned short*)(ws + WS_OB);
    unsigned short* wt    = (unsigned short*)(ws + WS_WT);
    int*            nbrp  = (int*)(ws + WS_NBR);
    float*          invd  = (float*)(ws + WS_INVD);
    float*          ostatp= (float*)(ws + WS_OSTP);
    float*          ostat = (float*)(ws + WS_OST);
    float*          out   = (float*)d_out;
    // xh (bf16, 33.5MB) lives in the upper half of d_out; dead before kbn
    // overwrites d_out (stream-ordered).
    unsigned short* xh    = (unsigned short*)d_out + 16777216;

    ktrans<<<2048, 256, 0, stream>>>(x, xh, nbr, weight, nbrp, invd, wt, ostatp);
    kconv <<<1024, 256, 0, stream>>>(xh, wt, nbrp, invd, ob, ostatp);
    kred  <<<1,    256, 0, stream>>>(ostatp, ostat, gamma, beta);
    kbn   <<<2048, 256, 0, stream>>>(ob, out, ostat);
}